// Round 13
// baseline (573.948 us; speedup 1.0000x reference)
//
#include <hip/hip_runtime.h>
#include <hip/hip_bf16.h>
#include <math.h>

#define N_USERS 8192
#define DIMS    128
#define EDGES   262144
#define KCAND   131072
#define NTOT    (EDGES + KCAND)      // 393216
#define LISTCAP 131072
#define CAPB    512                  // per-block LDS staging capacity (entries)
#define NTILES  2080                 // triangular 64x64 tiles of 128x128
#define COS_THR 0.3f
#define EPS_SEL 6e-3f                // > hard error bound ~4e-3 of bf16 cos
#define LOGIT_MARGIN 2e-3f
#define DEADKEY 0xFFFFFFFFu

typedef short bf16x8  __attribute__((ext_vector_type(8)));
typedef float f32x16  __attribute__((ext_vector_type(16)));

// u0 tiled layout: slab (i>>7) of 16384 shorts; within slab:
//   [cq = k>>3 (16)][row = i&127 (128)][k&7 (8)]
// -> each slab is 32 KB contiguous (2048 uint4), byte-identical to the LDS
//    As/Bs image.

// ---------------------------------------------------------------------------
// 1) prep (fused): blocks 0..31 -> normalize (bit-exact vs numpy) + tiled
//    bf16 copy + per-user partial logits; blocks 32..1055 -> excl bitmask.
// ---------------------------------------------------------------------------
__global__ __launch_bounds__(256) void prep_k(const float* __restrict__ x,
                                              const float* __restrict__ W,
                                              const int* __restrict__ nz,
                                              float* __restrict__ un,
                                              unsigned short* __restrict__ u0,
                                              float4* __restrict__ P,
                                              unsigned* __restrict__ excl) {
  if (blockIdx.x < 32) {
#pragma clang fp contract(off)
    int i = blockIdx.x * 256 + threadIdx.x;
    const float* r = x + (size_t)i * DIMS;
    float a[8];
#pragma unroll
    for (int j = 0; j < 8; ++j) { float t = r[j]; a[j] = t * t; }
    for (int b8 = 8; b8 < DIMS; b8 += 8) {
#pragma unroll
      for (int j = 0; j < 8; ++j) { float t = r[b8 + j]; a[j] = a[j] + t * t; }
    }
    float s = ((a[0] + a[1]) + (a[2] + a[3])) + ((a[4] + a[5]) + (a[6] + a[7]));
    float n = (float)sqrt((double)s);
    n = fmaxf(n, 1e-12f);
    unsigned short* slab = u0 + (size_t)(i >> 7) * 16384 + (i & 127) * 8;
#pragma unroll
    for (int cq = 0; cq < 16; ++cq) {
      unsigned short tmp[8];
#pragma unroll
      for (int t = 0; t < 8; ++t) {
        float v = r[cq * 8 + t] / n;
        un[(size_t)i * DIMS + cq * 8 + t] = v;
        __hip_bfloat16 h = __float2bfloat16(v);
        tmp[t] = *(unsigned short*)&h;
      }
      *(uint4*)(slab + (size_t)cq * 1024) = *(uint4*)tmp;
    }
    float a0 = 0.f, b0 = 0.f, a1 = 0.f, b1 = 0.f;
    for (int k = 0; k < DIMS; ++k) {
      float t = r[k];
      a0 = fmaf(t, W[k], a0);
      b0 = fmaf(t, W[128 + k], b0);
      a1 = fmaf(t, W[256 + k], a1);
      b1 = fmaf(t, W[384 + k], b1);
    }
    P[i] = make_float4(a0, b0, a1, b1);
  } else {
    int t = (blockIdx.x - 32) * 256 + threadIdx.x;
    if (t < EDGES) {
      int i = nz[2 * t], j = nz[2 * t + 1];
      atomicOr(&excl[(size_t)i * 256 + (j >> 5)], 1u << (j & 31));
    }
  }
}

// ---------------------------------------------------------------------------
// 2) mfma_pass: 128x128 tiles, triangular, 2080 independent blocks of 256.
//    32x32x16 MFMA (wave tile 64x64 = 2x2 tiles, acc 64 VGPR; staging regs
//    dead before acc lives; LDS 68.5KB -> 2 blk/CU).  Fragment reads/block:
//    128 b128 (vs 192 with 16x16x32).  a/b frag = contiguous 16B at
//    [kc*2+half][row][8] (same slab image); C: col=lane&31,
//    row=(r&3)+8*(r>>2)+4*half (m74/m101-verified).
//    Single-shot K staging, ONE barrier; flat slab copies.
//    R12 bug fixed: slab = 2048 uint4 -> exactly 8 uint4/thread (g<2),
//    not 16 (the 2x overrun wrote past LDS -> SIGABRT).
// ---------------------------------------------------------------------------
__global__ __launch_bounds__(256) void mfma_pass(const unsigned short* __restrict__ u0,
                                                 uint2* __restrict__ list,
                                                 int* __restrict__ gcount) {
  __shared__ __align__(16) unsigned short As[16][128][8];  // 32 KB
  __shared__ __align__(16) unsigned short Bs[16][128][8];  // 32 KB
  __shared__ uint2 svec[CAPB];                             // 4 KB
  __shared__ int lcnt, lbase;

  const int tid  = threadIdx.x;
  const int lane = tid & 63;
  const int wv   = tid >> 6;
  const int khalf = lane >> 5;          // k-half for 32x32x16 fragments
  const int l31  = lane & 31;

  // triangular decode: (bi, bj) with bj >= bi over 64 tiles of 128
  int rem = blockIdx.x, bi = 0;
  while (rem >= 64 - bi) { rem -= 64 - bi; ++bi; }
  const int bj = bi + rem;
  const int I0 = bi * 128, J0 = bj * 128;
  const int moff = (wv & 1) * 64, noff = (wv >> 1) * 64;

  if (tid == 0) lcnt = 0;

  // ---- single-shot staging: flat slab copy, 2048 uint4 per matrix ----
  const uint4* __restrict__ Aslab = (const uint4*)(u0 + (size_t)bi * 16384);
  const uint4* __restrict__ Bslab = (const uint4*)(u0 + (size_t)bj * 16384);
#pragma unroll
  for (int g = 0; g < 2; ++g) {
    uint4 pa[4], pb[4];
#pragma unroll
    for (int it = 0; it < 4; ++it) {
      int idx = (g * 4 + it) * 256 + tid;   // 0..2047
      pa[it] = Aslab[idx];
      pb[it] = Bslab[idx];
    }
#pragma unroll
    for (int it = 0; it < 4; ++it) {
      int idx = (g * 4 + it) * 256 + tid;
      ((uint4*)As)[idx] = pa[it];
      ((uint4*)Bs)[idx] = pb[it];
    }
  }
  __syncthreads();   // the ONLY barrier before the epilogue

  f32x16 acc[2][2];
#pragma unroll
  for (int mt = 0; mt < 2; ++mt)
#pragma unroll
    for (int nt = 0; nt < 2; ++nt)
#pragma unroll
      for (int g = 0; g < 16; ++g) acc[mt][nt][g] = 0.f;

  // ---- K loop: 8 kc x (2 af + 2 bf b128 reads, 4 MFMAs), no barriers ----
#pragma unroll
  for (int kc = 0; kc < 8; ++kc) {
    bf16x8 af[2], bf[2];
#pragma unroll
    for (int mt = 0; mt < 2; ++mt)
      af[mt] = *(const bf16x8*)&As[kc * 2 + khalf][moff + mt * 32 + l31][0];
#pragma unroll
    for (int nt = 0; nt < 2; ++nt)
      bf[nt] = *(const bf16x8*)&Bs[kc * 2 + khalf][noff + nt * 32 + l31][0];
#pragma unroll
    for (int mt = 0; mt < 2; ++mt)
#pragma unroll
      for (int nt = 0; nt < 2; ++nt)
        acc[mt][nt] = __builtin_amdgcn_mfma_f32_32x32x16_bf16(
            af[mt], bf[nt], acc[mt][nt], 0, 0, 0);
  }

  // ---- epilogue: j > i only; emit pair + mirror (one LDS atomic) ----
#pragma unroll
  for (int mt = 0; mt < 2; ++mt)
#pragma unroll
    for (int nt = 0; nt < 2; ++nt)
#pragma unroll
      for (int r = 0; r < 16; ++r) {
        float v = acc[mt][nt][r];
        if (v > COS_THR - EPS_SEL) {
          int i = I0 + moff + mt * 32 + (r & 3) + 8 * (r >> 2) + 4 * khalf;
          int j = J0 + noff + nt * 32 + l31;
          if (j > i) {
            int idx = atomicAdd(&lcnt, 2);
            if (idx + 1 < CAPB) {
              svec[idx]     = make_uint2(((unsigned)i << 13) | j,
                                         __float_as_uint(v));
              svec[idx + 1] = make_uint2(((unsigned)j << 13) | i,
                                         __float_as_uint(v));
            }
          }
        }
      }

  __syncthreads();
  int n = min(lcnt, CAPB);
  if (tid == 0) lbase = atomicAdd(gcount, n);
  __syncthreads();
  int base = lbase;
  for (int t = tid; t < n; t += 256) {
    int o = base + t;
    if (o < LISTCAP) list[o] = svec[t];
  }
}

// ---------------------------------------------------------------------------
// 3) tail (fused, single block x 1024): resolve + histogram + scan +
//    scatter + per-row sort.  Pad eliminated — finalize fast-paths q >= M.
// ---------------------------------------------------------------------------
__global__ __launch_bounds__(1024) void tail_k(const float* __restrict__ un,
                                               const unsigned* __restrict__ excl,
                                               uint2* __restrict__ list,
                                               const int* __restrict__ gcount,
                                               int* __restrict__ gM,
                                               int* __restrict__ cand_i,
                                               int* __restrict__ cand_j,
                                               float* __restrict__ cand_v) {
  __shared__ int cnt[N_USERS];   // 32 KB: counts -> offsets
  __shared__ int pos[N_USERS];   // 32 KB: running positions (end markers)
  __shared__ int wsum[1024];     //  4 KB

  const int tid = threadIdx.x;
  for (int r = tid; r < N_USERS; r += 1024) cnt[r] = 0;
  __syncthreads();

  const int n = min(*gcount, LISTCAP);

  // ---- resolve + histogram ----
  for (int t = tid; t < n; t += 1024) {
    uint2 e = list[t];
    int i = e.x >> 13, j = e.x & 8191;
    unsigned word = excl[(size_t)i * 256 + (j >> 5)];
    bool alive = !(i == j || ((word >> (j & 31)) & 1u));
    float v = __uint_as_float(e.y);
    if (alive && v <= COS_THR + EPS_SEL) {   // borderline: decide exactly
      const float* a = un + (size_t)i * DIMS;
      const float* b = un + (size_t)j * DIMS;
      float s = 0.f;
      for (int k = 0; k < DIMS; ++k) s = fmaf(a[k], b[k], s);
      alive = (s > COS_THR);
      if (alive) list[t] = make_uint2(e.x, __float_as_uint(s));
    }
    if (!alive) list[t] = make_uint2(DEADKEY, 0u);
    else        atomicAdd(&cnt[i], 1);
  }
  __syncthreads();

  // ---- exclusive scan (1024 x 8 serial + Hillis-Steele) ----
  int local[8];
  int s = 0;
  {
    int base8 = tid * 8;
#pragma unroll
    for (int q = 0; q < 8; ++q) { local[q] = cnt[base8 + q]; s += local[q]; }
  }
  wsum[tid] = s;
  __syncthreads();
  int x = s;
  for (int d = 1; d < 1024; d <<= 1) {
    int y = (tid >= d) ? wsum[tid - d] : 0;
    __syncthreads();
    x += y;
    wsum[tid] = x;
    __syncthreads();
  }
  {
    int run = x - s;
    int base8 = tid * 8;
#pragma unroll
    for (int q = 0; q < 8; ++q) {
      cnt[base8 + q] = run;
      pos[base8 + q] = run;
      run += local[q];
    }
  }
  if (tid == 1023) *gM = x;   // total live count M
  __syncthreads();

  // ---- scatter ----
  for (int t = tid; t < n; t += 1024) {
    uint2 e = list[t];
    if (e.x != DEADKEY) {
      int i = e.x >> 13, j = e.x & 8191;
      int p = atomicAdd(&pos[i], 1);
      if (p < KCAND) {
        cand_i[p] = i;
        cand_j[p] = j;
        cand_v[p] = __uint_as_float(e.y);
      }
    }
  }
  __syncthreads();

  // ---- per-row insertion sort by j ----
  for (int r = tid; r < N_USERS; r += 1024) {
    int o = cnt[r];
    int e2 = min(pos[r], KCAND);
    for (int a = o + 1; a < e2; ++a) {
      int jv = cand_j[a];
      float vv = cand_v[a];
      int b = a - 1;
      while (b >= o && cand_j[b] > jv) {
        cand_j[b + 1] = cand_j[b];
        cand_v[b + 1] = cand_v[b];
        --b;
      }
      cand_j[b + 1] = jv;
      cand_v[b + 1] = vv;
    }
  }
}

// ---------------------------------------------------------------------------
// 4) finalize (split logits + exact-chain fallback near ties; q >= M
//    fast-path replaces the old pad kernel)
// ---------------------------------------------------------------------------
__global__ __launch_bounds__(256) void finalize_k(const float* __restrict__ ue,
                                                  const float* __restrict__ W,
                                                  const float* __restrict__ b,
                                                  const float* __restrict__ g,
                                                  const int* __restrict__ nz,
                                                  const int* __restrict__ cand_i,
                                                  const int* __restrict__ cand_j,
                                                  const float* __restrict__ cand_v,
                                                  const float4* __restrict__ P,
                                                  const int* __restrict__ gM,
                                                  float* __restrict__ out) {
  int p = blockIdx.x * 256 + threadIdx.x;
  if (p >= NTOT) return;

  int i, j;
  float wgt;
  if (p < EDGES) {
    i = nz[2 * p];
    j = nz[2 * p + 1];
    wgt = 1.0f;
  } else {
    int q = p - EDGES;
    if (q >= *gM) {
      // padded candidate: pair (0,0), weight max(cos[0,0]=-1, 0) = 0 -> w = 0
      out[p] = 0.f;
      out[NTOT + p] = 0.f;
      out[2 * NTOT + p] = 0.f;
      out[3 * NTOT + 2 * p + 0] = 0.f;
      out[3 * NTOT + 2 * p + 1] = 0.f;
      return;
    }
    i = cand_i[q];
    j = cand_j[q];
    wgt = fmaxf(cand_v[q], 0.0f);
  }

  float4 Pi = P[i], Pj = P[j];
  float l0 = Pi.x + Pj.y + b[0];
  float l1 = Pi.z + Pj.w + b[1];
  float g0 = g[2 * p], g1 = g[2 * p + 1];
  float s0 = l0 + g0, s1 = l1 + g1;

  if (fabsf(s0 - s1) < LOGIT_MARGIN) {
    const float* ri = ue + (size_t)i * DIMS;
    const float* rj = ue + (size_t)j * DIMS;
    float e0 = 0.f, e1 = 0.f;
    for (int k = 0; k < DIMS; ++k) {
      e0 = fmaf(ri[k], W[k], e0);
      e1 = fmaf(ri[k], W[256 + k], e1);
    }
    for (int k = 0; k < DIMS; ++k) {
      e0 = fmaf(rj[k], W[128 + k], e0);
      e1 = fmaf(rj[k], W[384 + k], e1);
    }
    s0 = (e0 + b[0]) + g0;
    s1 = (e1 + b[1]) + g1;
  }

  float w = (s0 >= s1) ? wgt : 0.0f;

  out[p] = w;
  out[NTOT + p] = w;
  out[2 * NTOT + p] = w;
  out[3 * NTOT + 2 * p + 0] = (float)i;
  out[3 * NTOT + 2 * p + 1] = (float)j;
}

// ---------------------------------------------------------------------------
extern "C" void kernel_launch(void* const* d_in, const int* in_sizes, int n_in,
                              void* d_out, int out_size, void* d_ws, size_t ws_size,
                              hipStream_t stream) {
  (void)in_sizes; (void)n_in; (void)out_size; (void)ws_size;

  const float* user_emb = (const float*)d_in[0];
  const float* W        = (const float*)d_in[1];
  const float* b        = (const float*)d_in[2];
  const float* gnoise   = (const float*)d_in[3];
  const int*   nz       = (const int*)d_in[4];
  float* out = (float*)d_out;

  char* ws = (char*)d_ws;
  float*          un      = (float*)(ws + 0);                        // 4 MB
  unsigned short* u0      = (unsigned short*)(ws + (4u << 20));      // 2 MB (tiled)
  unsigned*       excl    = (unsigned*)(ws + (6u << 20));            // 8 MB
  // zeroed region directly after excl: gcount | gM
  char*           zbase   = ws + (14u << 20);
  int*            gcount  = (int*)(zbase);
  int*            gM      = (int*)(zbase + 64);
  uint2*          list    = (uint2*)(ws + (15u << 20));              // 1 MB
  int*            cand_i  = (int*)(ws + (16u << 20));                // 512 KB
  int*            cand_j  = (int*)(ws + (16u << 20) + (512u << 10)); // 512 KB
  float*          cand_v  = (float*)(ws + (17u << 20));              // 512 KB
  float4*         P       = (float4*)(ws + (17u << 20) + (512u << 10)); // 128 KB

  // one memset: excl (8 MB) + counter slots (contiguous)
  hipMemsetAsync(excl, 0, (8u << 20) + 128, stream);

  prep_k<<<32 + EDGES / 256, 256, 0, stream>>>(user_emb, W, nz, un, u0, P, excl);
  mfma_pass<<<NTILES, 256, 0, stream>>>(u0, list, gcount);
  tail_k<<<1, 1024, 0, stream>>>(un, excl, list, gcount, gM,
                                 cand_i, cand_j, cand_v);
  finalize_k<<<NTOT / 256, 256, 0, stream>>>(user_emb, W, b, gnoise, nz,
                                             cand_i, cand_j, cand_v, P, gM, out);
}

// Round 15
// 164.812 us; speedup vs baseline: 3.4824x; 3.4824x over previous
//
#include <hip/hip_runtime.h>
#include <hip/hip_bf16.h>
#include <math.h>

#define N_USERS 8192
#define DIMS    128
#define EDGES   262144
#define KCAND   131072
#define NTOT    (EDGES + KCAND)      // 393216
#define LISTCAP 131072
#define CAPB    512                  // per-block LDS staging capacity (entries)
#define NTILES  2080                 // triangular 64x64 tiles of 128x128
#define COS_THR 0.3f
#define EPS_SEL 6e-3f                // > hard error bound ~4e-3 of bf16 cos
#define LOGIT_MARGIN 2e-3f
#define DEADKEY 0xFFFFFFFFu

typedef short bf16x8  __attribute__((ext_vector_type(8)));
typedef float f32x16  __attribute__((ext_vector_type(16)));

// u0 tiled layout: slab (i>>7) of 16384 shorts; within slab:
//   [cq = k>>3 (16)][row = i&127 (128)][k&7 (8)]
// -> each slab is 32 KB contiguous (2048 uint4), byte-identical to the LDS
//    As/Bs image.

// ---------------------------------------------------------------------------
// 1) prep (fused): blocks 0..31 -> normalize (bit-exact vs numpy) + tiled
//    bf16 copy + per-user partial logits; blocks 32..1055 -> excl bitmask.
// ---------------------------------------------------------------------------
__global__ __launch_bounds__(256) void prep_k(const float* __restrict__ x,
                                              const float* __restrict__ W,
                                              const int* __restrict__ nz,
                                              float* __restrict__ un,
                                              unsigned short* __restrict__ u0,
                                              float4* __restrict__ P,
                                              unsigned* __restrict__ excl) {
  if (blockIdx.x < 32) {
#pragma clang fp contract(off)
    int i = blockIdx.x * 256 + threadIdx.x;
    const float* r = x + (size_t)i * DIMS;
    float a[8];
#pragma unroll
    for (int j = 0; j < 8; ++j) { float t = r[j]; a[j] = t * t; }
    for (int b8 = 8; b8 < DIMS; b8 += 8) {
#pragma unroll
      for (int j = 0; j < 8; ++j) { float t = r[b8 + j]; a[j] = a[j] + t * t; }
    }
    float s = ((a[0] + a[1]) + (a[2] + a[3])) + ((a[4] + a[5]) + (a[6] + a[7]));
    float n = (float)sqrt((double)s);
    n = fmaxf(n, 1e-12f);
    unsigned short* slab = u0 + (size_t)(i >> 7) * 16384 + (i & 127) * 8;
#pragma unroll
    for (int cq = 0; cq < 16; ++cq) {
      unsigned short tmp[8];
#pragma unroll
      for (int t = 0; t < 8; ++t) {
        float v = r[cq * 8 + t] / n;
        un[(size_t)i * DIMS + cq * 8 + t] = v;
        __hip_bfloat16 h = __float2bfloat16(v);
        tmp[t] = *(unsigned short*)&h;
      }
      *(uint4*)(slab + (size_t)cq * 1024) = *(uint4*)tmp;
    }
    float a0 = 0.f, b0 = 0.f, a1 = 0.f, b1 = 0.f;
    for (int k = 0; k < DIMS; ++k) {
      float t = r[k];
      a0 = fmaf(t, W[k], a0);
      b0 = fmaf(t, W[128 + k], b0);
      a1 = fmaf(t, W[256 + k], a1);
      b1 = fmaf(t, W[384 + k], b1);
    }
    P[i] = make_float4(a0, b0, a1, b1);
  } else {
    int t = (blockIdx.x - 32) * 256 + threadIdx.x;
    if (t < EDGES) {
      int i = nz[2 * t], j = nz[2 * t + 1];
      atomicOr(&excl[(size_t)i * 256 + (j >> 5)], 1u << (j & 31));
    }
  }
}

// ---------------------------------------------------------------------------
// 2) mfma_pass: 128x128 tiles, triangular, 2080 independent blocks of 256.
//    32x32x16 MFMA (wave tile 64x64 = 2x2 tiles, acc 64 VGPR; LDS 68.5KB ->
//    2 blk/CU).  128 fragment-b128 reads/block.  Single-shot K staging, ONE
//    barrier; flat slab copies (2048 uint4/matrix, 8/thread).
// ---------------------------------------------------------------------------
__global__ __launch_bounds__(256) void mfma_pass(const unsigned short* __restrict__ u0,
                                                 uint2* __restrict__ list,
                                                 int* __restrict__ gcount) {
  __shared__ __align__(16) unsigned short As[16][128][8];  // 32 KB
  __shared__ __align__(16) unsigned short Bs[16][128][8];  // 32 KB
  __shared__ uint2 svec[CAPB];                             // 4 KB
  __shared__ int lcnt, lbase;

  const int tid  = threadIdx.x;
  const int lane = tid & 63;
  const int wv   = tid >> 6;
  const int khalf = lane >> 5;          // k-half for 32x32x16 fragments
  const int l31  = lane & 31;

  // triangular decode: (bi, bj) with bj >= bi over 64 tiles of 128
  int rem = blockIdx.x, bi = 0;
  while (rem >= 64 - bi) { rem -= 64 - bi; ++bi; }
  const int bj = bi + rem;
  const int I0 = bi * 128, J0 = bj * 128;
  const int moff = (wv & 1) * 64, noff = (wv >> 1) * 64;

  if (tid == 0) lcnt = 0;

  // ---- single-shot staging: flat slab copy, 2048 uint4 per matrix ----
  const uint4* __restrict__ Aslab = (const uint4*)(u0 + (size_t)bi * 16384);
  const uint4* __restrict__ Bslab = (const uint4*)(u0 + (size_t)bj * 16384);
#pragma unroll
  for (int g = 0; g < 2; ++g) {
    uint4 pa[4], pb[4];
#pragma unroll
    for (int it = 0; it < 4; ++it) {
      int idx = (g * 4 + it) * 256 + tid;   // 0..2047
      pa[it] = Aslab[idx];
      pb[it] = Bslab[idx];
    }
#pragma unroll
    for (int it = 0; it < 4; ++it) {
      int idx = (g * 4 + it) * 256 + tid;
      ((uint4*)As)[idx] = pa[it];
      ((uint4*)Bs)[idx] = pb[it];
    }
  }
  __syncthreads();   // the ONLY barrier before the epilogue

  f32x16 acc[2][2];
#pragma unroll
  for (int mt = 0; mt < 2; ++mt)
#pragma unroll
    for (int nt = 0; nt < 2; ++nt)
#pragma unroll
      for (int g = 0; g < 16; ++g) acc[mt][nt][g] = 0.f;

  // ---- K loop: 8 kc x (2 af + 2 bf b128 reads, 4 MFMAs), no barriers ----
#pragma unroll
  for (int kc = 0; kc < 8; ++kc) {
    bf16x8 af[2], bf[2];
#pragma unroll
    for (int mt = 0; mt < 2; ++mt)
      af[mt] = *(const bf16x8*)&As[kc * 2 + khalf][moff + mt * 32 + l31][0];
#pragma unroll
    for (int nt = 0; nt < 2; ++nt)
      bf[nt] = *(const bf16x8*)&Bs[kc * 2 + khalf][noff + nt * 32 + l31][0];
#pragma unroll
    for (int mt = 0; mt < 2; ++mt)
#pragma unroll
      for (int nt = 0; nt < 2; ++nt)
        acc[mt][nt] = __builtin_amdgcn_mfma_f32_32x32x16_bf16(
            af[mt], bf[nt], acc[mt][nt], 0, 0, 0);
  }

  // ---- epilogue: j > i only; emit pair + mirror (one LDS atomic) ----
#pragma unroll
  for (int mt = 0; mt < 2; ++mt)
#pragma unroll
    for (int nt = 0; nt < 2; ++nt)
#pragma unroll
      for (int r = 0; r < 16; ++r) {
        float v = acc[mt][nt][r];
        if (v > COS_THR - EPS_SEL) {
          int i = I0 + moff + mt * 32 + (r & 3) + 8 * (r >> 2) + 4 * khalf;
          int j = J0 + noff + nt * 32 + l31;
          if (j > i) {
            int idx = atomicAdd(&lcnt, 2);
            if (idx + 1 < CAPB) {
              svec[idx]     = make_uint2(((unsigned)i << 13) | j,
                                         __float_as_uint(v));
              svec[idx + 1] = make_uint2(((unsigned)j << 13) | i,
                                         __float_as_uint(v));
            }
          }
        }
      }

  __syncthreads();
  int n = min(lcnt, CAPB);
  if (tid == 0) lbase = atomicAdd(gcount, n);
  __syncthreads();
  int base = lbase;
  for (int t = tid; t < n; t += 256) {
    int o = base + t;
    if (o < LISTCAP) list[o] = svec[t];
  }
}

// ---------------------------------------------------------------------------
// 3) resolve + histogram — grid-wide (R13 lesson: never single-block fuse
//    latency-bound per-entry work).  float4 loads, k-order component fmafs.
// ---------------------------------------------------------------------------
__global__ __launch_bounds__(256) void resolve_hist_k(const float* __restrict__ un,
                                                      const unsigned* __restrict__ excl,
                                                      uint2* __restrict__ list,
                                                      const int* __restrict__ gcount,
                                                      int* __restrict__ row_cnt) {
  int t = blockIdx.x * 256 + threadIdx.x;
  int n = min(*gcount, LISTCAP);
  if (t >= n) return;
  uint2 e = list[t];
  int i = e.x >> 13, j = e.x & 8191;
  unsigned word = excl[(size_t)i * 256 + (j >> 5)];
  bool alive = !(i == j || ((word >> (j & 31)) & 1u));
  float v = __uint_as_float(e.y);
  if (alive && v <= COS_THR + EPS_SEL) {   // borderline: decide exactly
    const float4* a4 = (const float4*)(un + (size_t)i * DIMS);
    const float4* b4 = (const float4*)(un + (size_t)j * DIMS);
    float s = 0.f;
#pragma unroll
    for (int k4 = 0; k4 < 32; ++k4) {
      float4 av = a4[k4], bv = b4[k4];
      s = fmaf(av.x, bv.x, s);
      s = fmaf(av.y, bv.y, s);
      s = fmaf(av.z, bv.z, s);
      s = fmaf(av.w, bv.w, s);
    }
    alive = (s > COS_THR);
    if (alive) list[t] = make_uint2(e.x, __float_as_uint(s));
  }
  if (!alive) list[t] = make_uint2(DEADKEY, 0u);
  else        atomicAdd(&row_cnt[i], 1);
}

// ---------------------------------------------------------------------------
// 4) exclusive scan over 8192 row counts (single block); row_off[N_USERS]=M
// ---------------------------------------------------------------------------
__global__ __launch_bounds__(256) void scan8k(const int* __restrict__ cnt,
                                              int* __restrict__ off) {
  __shared__ int sm[256];
  int t = threadIdx.x;
  int base = t * 32;
  int s = 0;
  for (int i = 0; i < 32; ++i) s += cnt[base + i];
  sm[t] = s;
  __syncthreads();
  int x = s;
  for (int d = 1; d < 256; d <<= 1) {
    int y = (t >= d) ? sm[t - d] : 0;
    __syncthreads();
    x += y;
    sm[t] = x;
    __syncthreads();
  }
  int run = x - s;
  for (int i = 0; i < 32; ++i) { off[base + i] = run; run += cnt[base + i]; }
  if (t == 255) off[N_USERS] = x;
}

// 5) scatter live entries to per-row spans (grid-wide)
__global__ __launch_bounds__(256) void scatter_k(const uint2* __restrict__ list,
                                                 const int* __restrict__ gcount,
                                                 const int* __restrict__ row_off,
                                                 int* __restrict__ row_pos,
                                                 int* __restrict__ cand_i,
                                                 int* __restrict__ cand_j,
                                                 float* __restrict__ cand_v) {
  int t = blockIdx.x * 256 + threadIdx.x;
  int n = min(*gcount, LISTCAP);
  if (t >= n) return;
  uint2 e = list[t];
  if (e.x == DEADKEY) return;
  int i = e.x >> 13, j = e.x & 8191;
  int pos = row_off[i] + atomicAdd(&row_pos[i], 1);
  if (pos < KCAND) {
    cand_i[pos] = i;
    cand_j[pos] = j;
    cand_v[pos] = __uint_as_float(e.y);
  }
}

// 6) sort each row's span ascending by j (R11-proven form; R14's mangled
//    guard `b >= o` skipped sorting entirely -> pair_idx absmax 8153)
__global__ __launch_bounds__(256) void sortrow_k(const int* __restrict__ row_off,
                                                 const int* __restrict__ row_cnt,
                                                 int* __restrict__ cand_j,
                                                 float* __restrict__ cand_v) {
  int r = blockIdx.x * 256 + threadIdx.x;
  if (r >= N_USERS) return;
  int o = row_off[r], c = row_cnt[r];
  if (o + c > KCAND) c = max(0, KCAND - o);
  for (int a = 1; a < c; ++a) {
    int jv = cand_j[o + a];
    float vv = cand_v[o + a];
    int b = a - 1;
    while (b >= 0 && cand_j[o + b] > jv) {
      cand_j[o + b + 1] = cand_j[o + b];
      cand_v[o + b + 1] = cand_v[o + b];
      --b;
    }
    cand_j[o + b + 1] = jv;
    cand_v[o + b + 1] = vv;
  }
}

// ---------------------------------------------------------------------------
// 7) finalize (split logits + exact-chain fallback near ties; q >= M
//    fast-path replaces the pad kernel; gM = &row_off[N_USERS])
// ---------------------------------------------------------------------------
__global__ __launch_bounds__(256) void finalize_k(const float* __restrict__ ue,
                                                  const float* __restrict__ W,
                                                  const float* __restrict__ b,
                                                  const float* __restrict__ g,
                                                  const int* __restrict__ nz,
                                                  const int* __restrict__ cand_i,
                                                  const int* __restrict__ cand_j,
                                                  const float* __restrict__ cand_v,
                                                  const float4* __restrict__ P,
                                                  const int* __restrict__ gM,
                                                  float* __restrict__ out) {
  int p = blockIdx.x * 256 + threadIdx.x;
  if (p >= NTOT) return;

  int i, j;
  float wgt;
  if (p < EDGES) {
    i = nz[2 * p];
    j = nz[2 * p + 1];
    wgt = 1.0f;
  } else {
    int q = p - EDGES;
    if (q >= *gM) {
      // padded candidate: pair (0,0), weight max(cos[0,0]=-1, 0) = 0 -> w = 0
      out[p] = 0.f;
      out[NTOT + p] = 0.f;
      out[2 * NTOT + p] = 0.f;
      out[3 * NTOT + 2 * p + 0] = 0.f;
      out[3 * NTOT + 2 * p + 1] = 0.f;
      return;
    }
    i = cand_i[q];
    j = cand_j[q];
    wgt = fmaxf(cand_v[q], 0.0f);
  }

  float4 Pi = P[i], Pj = P[j];
  float l0 = Pi.x + Pj.y + b[0];
  float l1 = Pi.z + Pj.w + b[1];
  float g0 = g[2 * p], g1 = g[2 * p + 1];
  float s0 = l0 + g0, s1 = l1 + g1;

  if (fabsf(s0 - s1) < LOGIT_MARGIN) {
    const float4* ri = (const float4*)(ue + (size_t)i * DIMS);
    const float4* rj = (const float4*)(ue + (size_t)j * DIMS);
    float e0 = 0.f, e1 = 0.f;
#pragma unroll
    for (int k4 = 0; k4 < 32; ++k4) {
      float4 av = ri[k4];
      e0 = fmaf(av.x, W[k4 * 4 + 0], e0);
      e0 = fmaf(av.y, W[k4 * 4 + 1], e0);
      e0 = fmaf(av.z, W[k4 * 4 + 2], e0);
      e0 = fmaf(av.w, W[k4 * 4 + 3], e0);
      e1 = fmaf(av.x, W[256 + k4 * 4 + 0], e1);
      e1 = fmaf(av.y, W[256 + k4 * 4 + 1], e1);
      e1 = fmaf(av.z, W[256 + k4 * 4 + 2], e1);
      e1 = fmaf(av.w, W[256 + k4 * 4 + 3], e1);
    }
#pragma unroll
    for (int k4 = 0; k4 < 32; ++k4) {
      float4 bv = rj[k4];
      e0 = fmaf(bv.x, W[128 + k4 * 4 + 0], e0);
      e0 = fmaf(bv.y, W[128 + k4 * 4 + 1], e0);
      e0 = fmaf(bv.z, W[128 + k4 * 4 + 2], e0);
      e0 = fmaf(bv.w, W[128 + k4 * 4 + 3], e0);
      e1 = fmaf(bv.x, W[384 + k4 * 4 + 0], e1);
      e1 = fmaf(bv.y, W[384 + k4 * 4 + 1], e1);
      e1 = fmaf(bv.z, W[384 + k4 * 4 + 2], e1);
      e1 = fmaf(bv.w, W[384 + k4 * 4 + 3], e1);
    }
    s0 = (e0 + b[0]) + g0;
    s1 = (e1 + b[1]) + g1;
  }

  float w = (s0 >= s1) ? wgt : 0.0f;

  out[p] = w;
  out[NTOT + p] = w;
  out[2 * NTOT + p] = w;
  out[3 * NTOT + 2 * p + 0] = (float)i;
  out[3 * NTOT + 2 * p + 1] = (float)j;
}

// ---------------------------------------------------------------------------
extern "C" void kernel_launch(void* const* d_in, const int* in_sizes, int n_in,
                              void* d_out, int out_size, void* d_ws, size_t ws_size,
                              hipStream_t stream) {
  (void)in_sizes; (void)n_in; (void)out_size; (void)ws_size;

  const float* user_emb = (const float*)d_in[0];
  const float* W        = (const float*)d_in[1];
  const float* b        = (const float*)d_in[2];
  const float* gnoise   = (const float*)d_in[3];
  const int*   nz       = (const int*)d_in[4];
  float* out = (float*)d_out;

  char* ws = (char*)d_ws;
  float*          un      = (float*)(ws + 0);                        // 4 MB
  unsigned short* u0      = (unsigned short*)(ws + (4u << 20));      // 2 MB (tiled)
  unsigned*       excl    = (unsigned*)(ws + (6u << 20));            // 8 MB
  // zeroed region directly after excl: gcount | row_cnt | row_pos
  char*           zbase   = ws + (14u << 20);
  int*            gcount  = (int*)(zbase);                           // 64 B slot
  int*            row_cnt = (int*)(zbase + 64);                      // 32 KB
  int*            row_pos = (int*)(zbase + 64 + 32768);              // 32 KB
  int*            row_off = (int*)(ws + (14u << 20) + (96u << 10));  // 32.8 KB
  uint2*          list    = (uint2*)(ws + (15u << 20));              // 1 MB
  int*            cand_i  = (int*)(ws + (16u << 20));                // 512 KB
  int*            cand_j  = (int*)(ws + (16u << 20) + (512u << 10)); // 512 KB
  float*          cand_v  = (float*)(ws + (17u << 20));              // 512 KB
  float4*         P       = (float4*)(ws + (17u << 20) + (512u << 10)); // 128 KB

  // one memset: excl (8 MB) + gcount/row_cnt/row_pos (96 KB, contiguous)
  hipMemsetAsync(excl, 0, (8u << 20) + (96u << 10), stream);

  prep_k<<<32 + EDGES / 256, 256, 0, stream>>>(user_emb, W, nz, un, u0, P, excl);
  mfma_pass<<<NTILES, 256, 0, stream>>>(u0, list, gcount);
  resolve_hist_k<<<LISTCAP / 256, 256, 0, stream>>>(un, excl, list, gcount,
                                                    row_cnt);
  scan8k<<<1, 256, 0, stream>>>(row_cnt, row_off);
  scatter_k<<<LISTCAP / 256, 256, 0, stream>>>(list, gcount, row_off, row_pos,
                                               cand_i, cand_j, cand_v);
  sortrow_k<<<N_USERS / 256, 256, 0, stream>>>(row_off, row_cnt, cand_j, cand_v);
  finalize_k<<<NTOT / 256, 256, 0, stream>>>(user_emb, W, b, gnoise, nz,
                                             cand_i, cand_j, cand_v, P,
                                             row_off + N_USERS, out);
}